// Round 1
// baseline (1273.031 us; speedup 1.0000x reference)
//
#include <hip/hip_runtime.h>
#include <cstdint>
#include <cstddef>

#define N_NODES 100000
#define N_EDGES 3200000
#define MPAD    100096   // 782 * 128
#define HID     256

typedef _Float16 f16;
typedef _Float16 f16x8 __attribute__((ext_vector_type(8)));
typedef float    f32x4 __attribute__((ext_vector_type(4)));

union F16x2 { unsigned u; f16 h[2]; };
__device__ inline void unpack2(unsigned u, float& a, float& b) {
    F16x2 x; x.u = u; a = (float)x.h[0]; b = (float)x.h[1];
}
__device__ inline unsigned pack2(float a, float b) {
    F16x2 x; x.h[0] = (f16)a; x.h[1] = (f16)b; return x.u;
}

// ---------------- CSR build ----------------
__global__ void k_count(const int* __restrict__ dst, int* __restrict__ deg, int e) {
    int i = blockIdx.x * 256 + threadIdx.x;
    if (i < e) atomicAdd(&deg[dst[i]], 1);
}

__global__ void k_bsum(const int* __restrict__ deg, int* __restrict__ bsum, int n) {
    int i = blockIdx.x * 256 + threadIdx.x;
    int v = (i < n) ? deg[i] : 0;
#pragma unroll
    for (int off = 32; off > 0; off >>= 1) v += __shfl_down(v, off);
    __shared__ int s[4];
    int lane = threadIdx.x & 63, w = threadIdx.x >> 6;
    if (lane == 0) s[w] = v;
    __syncthreads();
    if (threadIdx.x == 0) bsum[blockIdx.x] = s[0] + s[1] + s[2] + s[3];
}

__global__ void k_scanb(int* __restrict__ bsum, int* __restrict__ rowptrN, int nb, int total) {
    __shared__ int s[512];
    int t = threadIdx.x;
    int me = (t < nb) ? bsum[t] : 0;
    s[t] = me;
    __syncthreads();
    for (int off = 1; off < 512; off <<= 1) {
        int v = (t >= off) ? s[t - off] : 0;
        __syncthreads();
        s[t] += v;
        __syncthreads();
    }
    if (t < nb) bsum[t] = s[t] - me;           // exclusive block offsets
    if (t == 0) *rowptrN = total;              // rowptr[N] = E
}

__global__ void k_scanc(const int* __restrict__ deg, const int* __restrict__ boff,
                        int* __restrict__ rowptr, int* __restrict__ cur, int n) {
    int i = blockIdx.x * 256 + threadIdx.x;
    int v = (i < n) ? deg[i] : 0;
    int lane = threadIdx.x & 63, w = threadIdx.x >> 6;
    int x = v;
#pragma unroll
    for (int off = 1; off < 64; off <<= 1) {
        int y = __shfl_up(x, off);
        if (lane >= off) x += y;
    }
    __shared__ int ws_[4];
    if (lane == 63) ws_[w] = x;
    __syncthreads();
    int add = 0;
    for (int j = 0; j < w; ++j) add += ws_[j];
    int excl = boff[blockIdx.x] + add + x - v;
    if (i < n) { rowptr[i] = excl; cur[i] = excl; }
}

__global__ void k_fill(const int* __restrict__ src, const int* __restrict__ dst,
                       int* __restrict__ cur, int* __restrict__ ci, int e) {
    int i = blockIdx.x * 256 + threadIdx.x;
    if (i < e) {
        int p = atomicAdd(&cur[dst[i]], 1);
        ci[p] = src[i];
    }
}

// ---------------- dtype prep ----------------
__global__ void k_cvt(const float2* __restrict__ x, unsigned* __restrict__ o, int n) {
    int t = blockIdx.x * 256 + threadIdx.x;
    if (t < n) { float2 v = x[t]; o[t] = pack2(v.x, v.y); }
}

// W [K][256] fp32 row-major -> Wt [256][K] fp16, BN scale folded into columns
__global__ void k_foldw1(const float* __restrict__ W, const float* __restrict__ b1,
                         const float* __restrict__ gm, const float* __restrict__ bt,
                         const float* __restrict__ mu, const float* __restrict__ vr,
                         f16* __restrict__ Wt, float* __restrict__ bias, int K) {
    int t = blockIdx.x * 256 + threadIdx.x;
    if (t >= K * 256) return;
    int n = t & 255, k = t >> 8;
    float sc = gm[n] * rsqrtf(vr[n] + 1e-5f);
    Wt[n * K + k] = (f16)(W[t] * sc);
    if (k == 0) bias[n] = (b1[n] - mu[n]) * sc + bt[n];
}

__global__ void k_transb(const float* __restrict__ W, f16* __restrict__ Wt) {
    int t = blockIdx.x * 256 + threadIdx.x; // 65536
    int n = t & 255, k = t >> 8;
    Wt[n * 256 + k] = (f16)W[t];
}

// ---------------- aggregation: z = h + sum_{j->i} h_j ----------------
// one wave per node; 256-wide rows: lane holds 4 fp16 (uint2)
__global__ void k_agg256(const uint2* __restrict__ h, const int* __restrict__ rp,
                         const int* __restrict__ ci, uint2* __restrict__ z, int n) {
    int gw = (blockIdx.x * 256 + threadIdx.x) >> 6;
    if (gw >= n) return;
    int lane = threadIdx.x & 63;
    uint2 d = h[(size_t)gw * 64 + lane];
    float a0, a1, a2, a3, t0, t1;
    unpack2(d.x, a0, a1); unpack2(d.y, a2, a3);
    int s = rp[gw], e = rp[gw + 1];
    int p = s;
    for (; p + 1 < e; p += 2) {
        int j0 = ci[p], j1 = ci[p + 1];
        uint2 d0 = h[(size_t)j0 * 64 + lane];
        uint2 d1 = h[(size_t)j1 * 64 + lane];
        unpack2(d0.x, t0, t1); a0 += t0; a1 += t1;
        unpack2(d0.y, t0, t1); a2 += t0; a3 += t1;
        unpack2(d1.x, t0, t1); a0 += t0; a1 += t1;
        unpack2(d1.y, t0, t1); a2 += t0; a3 += t1;
    }
    if (p < e) {
        int j0 = ci[p];
        uint2 d0 = h[(size_t)j0 * 64 + lane];
        unpack2(d0.x, t0, t1); a0 += t0; a1 += t1;
        unpack2(d0.y, t0, t1); a2 += t0; a3 += t1;
    }
    uint2 o; o.x = pack2(a0, a1); o.y = pack2(a2, a3);
    z[(size_t)gw * 64 + lane] = o;
}

// 128-wide rows (layer-1 input x): lane holds 2 fp16 (uint)
__global__ void k_agg128(const unsigned* __restrict__ h, const int* __restrict__ rp,
                         const int* __restrict__ ci, unsigned* __restrict__ z, int n) {
    int gw = (blockIdx.x * 256 + threadIdx.x) >> 6;
    if (gw >= n) return;
    int lane = threadIdx.x & 63;
    float a0, a1, t0, t1;
    unpack2(h[(size_t)gw * 64 + lane], a0, a1);
    int s = rp[gw], e = rp[gw + 1];
    int p = s;
    for (; p + 1 < e; p += 2) {
        int j0 = ci[p], j1 = ci[p + 1];
        unsigned d0 = h[(size_t)j0 * 64 + lane];
        unsigned d1 = h[(size_t)j1 * 64 + lane];
        unpack2(d0, t0, t1); a0 += t0; a1 += t1;
        unpack2(d1, t0, t1); a0 += t0; a1 += t1;
    }
    if (p < e) {
        unpack2(h[(size_t)ci[p] * 64 + lane], t0, t1); a0 += t0; a1 += t1;
    }
    z[(size_t)gw * 64 + lane] = pack2(a0, a1);
}

// ---------------- GEMM: C[MPAD][256] = A[MPAD][K] @ Bt[256][K]^T (+bias, relu) ----------------
// 128x128 tile, 4 waves of 64x64, mfma 16x16x32 f16, global_load_lds 16B staging,
// XOR-swizzled LDS chunk layout: chunk(m, g) at slot m*8 + (g ^ (m&7))  (kills bank conflicts)
template <int K, bool RELU>
__global__ __launch_bounds__(256) void k_gemm(const f16* __restrict__ A,
                                              const f16* __restrict__ Bt,
                                              const float* __restrict__ bias,
                                              f16* __restrict__ C) {
    __shared__ f16 As[128 * 64];
    __shared__ f16 Bs[128 * 64];
    const int tid = threadIdx.x;
    const int bm0 = blockIdx.x * 128;
    const int bn0 = blockIdx.y * 128;
    const int lane = tid & 63, wave = tid >> 6;
    const int quad = lane >> 4, l16 = lane & 15;
    const int wr = (wave >> 1) * 64, wc = (wave & 1) * 64;
    f32x4 acc[4][4] = {};
    const f16* Abase = A + (size_t)bm0 * K;
    const f16* Bbase = Bt + (size_t)bn0 * K;

    for (int k0 = 0; k0 < K; k0 += 64) {
#pragma unroll
        for (int i = 0; i < 4; ++i) {
            int c = i * 256 + tid;      // 16B chunk id, lane-contiguous per wave
            int m = c >> 3;             // tile row
            int gg = (c & 7) ^ (m & 7); // global k-group (XOR swizzle)
            __builtin_amdgcn_global_load_lds(
                (const __attribute__((address_space(1))) unsigned int*)(Abase + (size_t)m * K + k0 + gg * 8),
                (__attribute__((address_space(3))) unsigned int*)(As + (size_t)c * 8), 16, 0, 0);
            __builtin_amdgcn_global_load_lds(
                (const __attribute__((address_space(1))) unsigned int*)(Bbase + (size_t)m * K + k0 + gg * 8),
                (__attribute__((address_space(3))) unsigned int*)(Bs + (size_t)c * 8), 16, 0, 0);
        }
        __syncthreads();
#pragma unroll
        for (int kk = 0; kk < 64; kk += 32) {
            const int gbase = kk >> 3; // 0 or 4
            f16x8 af[4], bfv[4];
#pragma unroll
            for (int mi = 0; mi < 4; ++mi) {
                int m = wr + mi * 16 + l16;
                int slot = (gbase + quad) ^ (m & 7);
                af[mi] = *(const f16x8*)&As[(m * 8 + slot) * 8];
            }
#pragma unroll
            for (int ni = 0; ni < 4; ++ni) {
                int m = wc + ni * 16 + l16;
                int slot = (gbase + quad) ^ (m & 7);
                bfv[ni] = *(const f16x8*)&Bs[(m * 8 + slot) * 8];
            }
#pragma unroll
            for (int mi = 0; mi < 4; ++mi)
#pragma unroll
                for (int ni = 0; ni < 4; ++ni)
                    acc[mi][ni] = __builtin_amdgcn_mfma_f32_16x16x32_f16(af[mi], bfv[ni], acc[mi][ni], 0, 0, 0);
        }
        __syncthreads();
    }

    float bv[4];
#pragma unroll
    for (int ni = 0; ni < 4; ++ni) bv[ni] = bias[bn0 + wc + ni * 16 + l16];
#pragma unroll
    for (int mi = 0; mi < 4; ++mi) {
#pragma unroll
        for (int r = 0; r < 4; ++r) {
            size_t row = (size_t)(bm0 + wr + mi * 16 + quad * 4 + r);
            f16* crow = C + row * HID + bn0 + wc + l16;
#pragma unroll
            for (int ni = 0; ni < 4; ++ni) {
                float v = acc[mi][ni][r] + bv[ni];
                if (RELU) v = fmaxf(v, 0.f);
                crow[ni * 16] = (f16)v;
            }
        }
    }
}

// ---------------- output head: out[N][2] = h @ W[256][2] + b ----------------
__global__ void k_out(const uint2* __restrict__ h, const float* __restrict__ W,
                      const float* __restrict__ b, float* __restrict__ out, int n) {
    int gw = (blockIdx.x * 256 + threadIdx.x) >> 6;
    if (gw >= n) return;
    int lane = threadIdx.x & 63;
    uint2 d = h[(size_t)gw * 64 + lane];
    float x0, x1, x2, x3;
    unpack2(d.x, x0, x1); unpack2(d.y, x2, x3);
    int k = lane * 4;
    float o0 = x0 * W[k * 2 + 0] + x1 * W[k * 2 + 2] + x2 * W[k * 2 + 4] + x3 * W[k * 2 + 6];
    float o1 = x0 * W[k * 2 + 1] + x1 * W[k * 2 + 3] + x2 * W[k * 2 + 5] + x3 * W[k * 2 + 7];
#pragma unroll
    for (int off = 32; off > 0; off >>= 1) {
        o0 += __shfl_down(o0, off);
        o1 += __shfl_down(o1, off);
    }
    if (lane == 0) {
        out[(size_t)gw * 2 + 0] = o0 + b[0];
        out[(size_t)gw * 2 + 1] = o1 + b[1];
    }
}

extern "C" void kernel_launch(void* const* d_in, const int* in_sizes, int n_in,
                              void* d_out, int out_size, void* d_ws, size_t ws_size,
                              hipStream_t stream) {
    const float* x    = (const float*)d_in[0];
    const int*   ei   = (const int*)d_in[1];
    const int*   esrc = ei;
    const int*   edst = ei + N_EDGES;
    // layer param base indices: l1=2, l2=10, l3=18; order: W1,b1,g,be,mu,var,W2,b2
    const float* lw[3][8];
    for (int l = 0; l < 3; ++l)
        for (int j = 0; j < 8; ++j) lw[l][j] = (const float*)d_in[2 + l * 8 + j];
    const float* outW = (const float*)d_in[26];
    const float* outB = (const float*)d_in[27];

    char* base = (char*)d_ws;
    size_t off = 0;
    auto alloc = [&](size_t bytes) -> void* {
        void* r = base + off;
        off += (bytes + 255) & ~(size_t)255;
        return r;
    };
    f16* z  = (f16*)alloc((size_t)MPAD * 256 * 2);   // agg output (layer1 uses [MPAD][128])
    f16* y  = (f16*)alloc((size_t)MPAD * 256 * 2);   // after W1
    f16* h  = (f16*)alloc((size_t)MPAD * 256 * 2);   // after W2 (layer output)
    f16* xh = (f16*)alloc((size_t)MPAD * 128 * 2);   // x as fp16
    f16* W1t[3]; float* bias1[3]; f16* W2t[3];
    W1t[0] = (f16*)alloc(256 * 128 * 2);
    W1t[1] = (f16*)alloc(256 * 256 * 2);
    W1t[2] = (f16*)alloc(256 * 256 * 2);
    for (int l = 0; l < 3; ++l) W2t[l] = (f16*)alloc(256 * 256 * 2);
    for (int l = 0; l < 3; ++l) bias1[l] = (float*)alloc(256 * 4);
    int* deg    = (int*)alloc((size_t)N_NODES * 4);
    int* cur    = (int*)alloc((size_t)N_NODES * 4);
    int* rowptr = (int*)alloc((size_t)(N_NODES + 1) * 4);
    int* colidx = (int*)alloc((size_t)N_EDGES * 4);
    int* bsum   = (int*)alloc(512 * 4);

    const int NB = (N_NODES + 255) / 256; // 391
    // CSR build
    hipMemsetAsync(deg, 0, (size_t)N_NODES * 4, stream);
    k_count<<<N_EDGES / 256, 256, 0, stream>>>(edst, deg, N_EDGES);
    k_bsum<<<NB, 256, 0, stream>>>(deg, bsum, N_NODES);
    k_scanb<<<1, 512, 0, stream>>>(bsum, rowptr + N_NODES, NB, N_EDGES);
    k_scanc<<<NB, 256, 0, stream>>>(deg, bsum, rowptr, cur, N_NODES);
    k_fill<<<N_EDGES / 256, 256, 0, stream>>>(esrc, edst, cur, colidx, N_EDGES);
    // dtype prep
    k_cvt<<<(N_NODES * 64 + 255) / 256, 256, 0, stream>>>((const float2*)x, (unsigned*)xh, N_NODES * 64);
    k_foldw1<<<128, 256, 0, stream>>>(lw[0][0], lw[0][1], lw[0][2], lw[0][3], lw[0][4], lw[0][5], W1t[0], bias1[0], 128);
    k_foldw1<<<256, 256, 0, stream>>>(lw[1][0], lw[1][1], lw[1][2], lw[1][3], lw[1][4], lw[1][5], W1t[1], bias1[1], 256);
    k_foldw1<<<256, 256, 0, stream>>>(lw[2][0], lw[2][1], lw[2][2], lw[2][3], lw[2][4], lw[2][5], W1t[2], bias1[2], 256);
    for (int l = 0; l < 3; ++l)
        k_transb<<<256, 256, 0, stream>>>(lw[l][6], W2t[l]);

    const dim3 ggrid(MPAD / 128, 2);
    const int AGG_BLOCKS = (N_NODES + 3) / 4; // one wave per node

    // layer 1
    k_agg128<<<AGG_BLOCKS, 256, 0, stream>>>((const unsigned*)xh, rowptr, colidx, (unsigned*)z, N_NODES);
    k_gemm<128, true><<<ggrid, 256, 0, stream>>>(z, W1t[0], bias1[0], y);
    k_gemm<256, true><<<ggrid, 256, 0, stream>>>(y, W2t[0], lw[0][7], h);
    // layer 2
    k_agg256<<<AGG_BLOCKS, 256, 0, stream>>>((const uint2*)h, rowptr, colidx, (uint2*)z, N_NODES);
    k_gemm<256, true><<<ggrid, 256, 0, stream>>>(z, W1t[1], bias1[1], y);
    k_gemm<256, true><<<ggrid, 256, 0, stream>>>(y, W2t[1], lw[1][7], h);
    // layer 3 (no final relu)
    k_agg256<<<AGG_BLOCKS, 256, 0, stream>>>((const uint2*)h, rowptr, colidx, (uint2*)z, N_NODES);
    k_gemm<256, true><<<ggrid, 256, 0, stream>>>(z, W1t[2], bias1[2], y);
    k_gemm<256, false><<<ggrid, 256, 0, stream>>>(y, W2t[2], lw[2][7], h);
    // output head
    k_out<<<AGG_BLOCKS, 256, 0, stream>>>((const uint2*)h, outW, outB, (float*)d_out, N_NODES);
}

// Round 2
// 1069.811 us; speedup vs baseline: 1.1900x; 1.1900x over previous
//
#include <hip/hip_runtime.h>
#include <cstdint>
#include <cstddef>

#define N_NODES 100000
#define N_EDGES 3200000
#define MPAD    100096   // 782 * 128
#define HID     256
#define NBUCK   196      // ceil(100000/512) buckets of 512 nodes
#define BSH     9        // 512 nodes per bucket
#define BSTRIDE 18432    // bucket region capacity (mean 16384 + 16 sigma)

typedef _Float16 f16;
typedef _Float16 f16x8 __attribute__((ext_vector_type(8)));
typedef float    f32x4 __attribute__((ext_vector_type(4)));

union F16x2 { unsigned u; f16 h[2]; };
__device__ inline void unpack2(unsigned u, float& a, float& b) {
    F16x2 x; x.u = u; a = (float)x.h[0]; b = (float)x.h[1];
}
__device__ inline unsigned pack2(float a, float b) {
    F16x2 x; x.h[0] = (f16)a; x.h[1] = (f16)b; return x.u;
}

// ---------------- CSR build: bucketed counting sort ----------------
// Pass A: distribute packed (dstLocal<<17 | src) edges into per-bucket regions.
// WG = 4096 edges; LDS histogram over 196 buckets; one global atomicAdd per
// (WG,bucket) reserves a dense run -> colidx-region lines get fully dirtied
// (write amp ~1x vs 15x for random 4B scatter).
__global__ __launch_bounds__(256) void k_bucketA(const int* __restrict__ src,
                                                 const int* __restrict__ dst,
                                                 unsigned* __restrict__ pairs,
                                                 int* __restrict__ nb, int e) {
    __shared__ int hist[NBUCK];
    __shared__ int lbase[NBUCK];
    __shared__ int lcur[NBUCK];
    const int t = threadIdx.x;
    for (int i = t; i < NBUCK; i += 256) hist[i] = 0;
    __syncthreads();
    const int e0 = blockIdx.x * 4096;
    bool v[16]; int d[16], s[16];
#pragma unroll
    for (int i = 0; i < 16; ++i) {
        int idx = e0 + i * 256 + t;
        v[i] = idx < e;
        d[i] = v[i] ? dst[idx] : 0;
        s[i] = v[i] ? src[idx] : 0;
    }
#pragma unroll
    for (int i = 0; i < 16; ++i)
        if (v[i]) atomicAdd(&hist[d[i] >> BSH], 1);
    __syncthreads();
    for (int i = t; i < NBUCK; i += 256) {
        int h = hist[i];
        lbase[i] = h ? atomicAdd(&nb[i], h) : 0;
        lcur[i] = 0;
    }
    __syncthreads();
#pragma unroll
    for (int i = 0; i < 16; ++i) {
        if (v[i]) {
            int b = d[i] >> BSH;
            int p = atomicAdd(&lcur[b], 1);
            unsigned packed = ((unsigned)(d[i] & 511) << 17) | (unsigned)s[i];
            pairs[(size_t)b * BSTRIDE + lbase[b] + p] = packed;
        }
    }
}

// exclusive prefix over 196 bucket counts -> bucket colidx bases; rowptr[N]=E
__global__ void k_scan196(const int* __restrict__ nb, int* __restrict__ bbase,
                          int* __restrict__ rowptrN) {
    __shared__ int s[256];
    int t = threadIdx.x;
    int v = (t < NBUCK) ? nb[t] : 0;
    s[t] = v;
    __syncthreads();
    for (int off = 1; off < 256; off <<= 1) {
        int u = (t >= off) ? s[t - off] : 0;
        __syncthreads();
        s[t] += u;
        __syncthreads();
    }
    if (t < NBUCK) bbase[t] = s[t] - v;
    if (t == 0) *rowptrN = N_EDGES;
}

// Pass B: one WG per bucket. LDS degree count + scan -> rowptr; scatter src
// into the bucket's contiguous (L2-hot, ~64KB) colidx window.
__global__ __launch_bounds__(256) void k_bucketB(const unsigned* __restrict__ pairs,
                                                 const int* __restrict__ nb,
                                                 const int* __restrict__ bbase,
                                                 int* __restrict__ rowptr,
                                                 int* __restrict__ colidx) {
    __shared__ int deg[512];
    __shared__ int sc[512];
    __shared__ int cur[512];
    const int b = blockIdx.x, t = threadIdx.x;
    const int cnt = nb[b], base = bbase[b];
    const unsigned* P = pairs + (size_t)b * BSTRIDE;
    deg[t] = 0; deg[t + 256] = 0;
    __syncthreads();
    for (int i = t; i < cnt; i += 256) atomicAdd(&deg[P[i] >> 17], 1);
    __syncthreads();
    sc[t] = deg[t]; sc[t + 256] = deg[t + 256];
    __syncthreads();
    for (int off = 1; off < 512; off <<= 1) {
        int a0 = (t >= off) ? sc[t - off] : 0;
        int a1 = (t + 256 >= off) ? sc[t + 256 - off] : 0;
        __syncthreads();
        sc[t] += a0; sc[t + 256] += a1;
        __syncthreads();
    }
    // exclusive + global base
    int node0 = b << BSH;
#pragma unroll
    for (int rep = 0; rep < 2; ++rep) {
        int i = t + rep * 256;
        int excl = base + sc[i] - deg[i];
        cur[i] = excl;
        int node = node0 + i;
        if (node < N_NODES) rowptr[node] = excl;
    }
    __syncthreads();
    for (int i = t; i < cnt; i += 256) {
        unsigned p = P[i];
        int pos = atomicAdd(&cur[p >> 17], 1);
        colidx[pos] = (int)(p & 0x1FFFF);
    }
}

// ---------------- dtype prep ----------------
__global__ void k_cvt(const float2* __restrict__ x, unsigned* __restrict__ o, int n) {
    int t = blockIdx.x * 256 + threadIdx.x;
    if (t < n) { float2 v = x[t]; o[t] = pack2(v.x, v.y); }
}

// W [K][256] fp32 row-major -> Wt [256][K] fp16, BN scale folded into columns
__global__ void k_foldw1(const float* __restrict__ W, const float* __restrict__ b1,
                         const float* __restrict__ gm, const float* __restrict__ bt,
                         const float* __restrict__ mu, const float* __restrict__ vr,
                         f16* __restrict__ Wt, float* __restrict__ bias, int K) {
    int t = blockIdx.x * 256 + threadIdx.x;
    if (t >= K * 256) return;
    int n = t & 255, k = t >> 8;
    float sc = gm[n] * rsqrtf(vr[n] + 1e-5f);
    Wt[n * K + k] = (f16)(W[t] * sc);
    if (k == 0) bias[n] = (b1[n] - mu[n]) * sc + bt[n];
}

__global__ void k_transb(const float* __restrict__ W, f16* __restrict__ Wt) {
    int t = blockIdx.x * 256 + threadIdx.x; // 65536
    int n = t & 255, k = t >> 8;
    Wt[n * 256 + k] = (f16)W[t];
}

// ---------------- aggregation: z = h + sum_{j->i} h_j ----------------
__global__ void k_agg256(const uint2* __restrict__ h, const int* __restrict__ rp,
                         const int* __restrict__ ci, uint2* __restrict__ z, int n) {
    int gw = (blockIdx.x * 256 + threadIdx.x) >> 6;
    if (gw >= n) return;
    int lane = threadIdx.x & 63;
    uint2 d = h[(size_t)gw * 64 + lane];
    float a0, a1, a2, a3, t0, t1;
    unpack2(d.x, a0, a1); unpack2(d.y, a2, a3);
    int s = rp[gw], e = rp[gw + 1];
    int p = s;
    for (; p + 1 < e; p += 2) {
        int j0 = ci[p], j1 = ci[p + 1];
        uint2 d0 = h[(size_t)j0 * 64 + lane];
        uint2 d1 = h[(size_t)j1 * 64 + lane];
        unpack2(d0.x, t0, t1); a0 += t0; a1 += t1;
        unpack2(d0.y, t0, t1); a2 += t0; a3 += t1;
        unpack2(d1.x, t0, t1); a0 += t0; a1 += t1;
        unpack2(d1.y, t0, t1); a2 += t0; a3 += t1;
    }
    if (p < e) {
        int j0 = ci[p];
        uint2 d0 = h[(size_t)j0 * 64 + lane];
        unpack2(d0.x, t0, t1); a0 += t0; a1 += t1;
        unpack2(d0.y, t0, t1); a2 += t0; a3 += t1;
    }
    uint2 o; o.x = pack2(a0, a1); o.y = pack2(a2, a3);
    z[(size_t)gw * 64 + lane] = o;
}

__global__ void k_agg128(const unsigned* __restrict__ h, const int* __restrict__ rp,
                         const int* __restrict__ ci, unsigned* __restrict__ z, int n) {
    int gw = (blockIdx.x * 256 + threadIdx.x) >> 6;
    if (gw >= n) return;
    int lane = threadIdx.x & 63;
    float a0, a1, t0, t1;
    unpack2(h[(size_t)gw * 64 + lane], a0, a1);
    int s = rp[gw], e = rp[gw + 1];
    int p = s;
    for (; p + 1 < e; p += 2) {
        int j0 = ci[p], j1 = ci[p + 1];
        unsigned d0 = h[(size_t)j0 * 64 + lane];
        unsigned d1 = h[(size_t)j1 * 64 + lane];
        unpack2(d0, t0, t1); a0 += t0; a1 += t1;
        unpack2(d1, t0, t1); a0 += t0; a1 += t1;
    }
    if (p < e) {
        unpack2(h[(size_t)ci[p] * 64 + lane], t0, t1); a0 += t0; a1 += t1;
    }
    z[(size_t)gw * 64 + lane] = pack2(a0, a1);
}

// ---------------- GEMM: C[MPAD][256] = A[MPAD][K] @ Bt[256][K]^T (+bias, relu) ----------------
template <int K, bool RELU>
__global__ __launch_bounds__(256) void k_gemm(const f16* __restrict__ A,
                                              const f16* __restrict__ Bt,
                                              const float* __restrict__ bias,
                                              f16* __restrict__ C) {
    __shared__ f16 As[128 * 64];
    __shared__ f16 Bs[128 * 64];
    const int tid = threadIdx.x;
    const int bm0 = blockIdx.x * 128;
    const int bn0 = blockIdx.y * 128;
    const int lane = tid & 63, wave = tid >> 6;
    const int quad = lane >> 4, l16 = lane & 15;
    const int wr = (wave >> 1) * 64, wc = (wave & 1) * 64;
    f32x4 acc[4][4] = {};
    const f16* Abase = A + (size_t)bm0 * K;
    const f16* Bbase = Bt + (size_t)bn0 * K;

    for (int k0 = 0; k0 < K; k0 += 64) {
#pragma unroll
        for (int i = 0; i < 4; ++i) {
            int c = i * 256 + tid;
            int m = c >> 3;
            int gg = (c & 7) ^ (m & 7);
            __builtin_amdgcn_global_load_lds(
                (const __attribute__((address_space(1))) unsigned int*)(Abase + (size_t)m * K + k0 + gg * 8),
                (__attribute__((address_space(3))) unsigned int*)(As + (size_t)c * 8), 16, 0, 0);
            __builtin_amdgcn_global_load_lds(
                (const __attribute__((address_space(1))) unsigned int*)(Bbase + (size_t)m * K + k0 + gg * 8),
                (__attribute__((address_space(3))) unsigned int*)(Bs + (size_t)c * 8), 16, 0, 0);
        }
        __syncthreads();
#pragma unroll
        for (int kk = 0; kk < 64; kk += 32) {
            const int gbase = kk >> 3;
            f16x8 af[4], bfv[4];
#pragma unroll
            for (int mi = 0; mi < 4; ++mi) {
                int m = wr + mi * 16 + l16;
                int slot = (gbase + quad) ^ (m & 7);
                af[mi] = *(const f16x8*)&As[(m * 8 + slot) * 8];
            }
#pragma unroll
            for (int ni = 0; ni < 4; ++ni) {
                int m = wc + ni * 16 + l16;
                int slot = (gbase + quad) ^ (m & 7);
                bfv[ni] = *(const f16x8*)&Bs[(m * 8 + slot) * 8];
            }
#pragma unroll
            for (int mi = 0; mi < 4; ++mi)
#pragma unroll
                for (int ni = 0; ni < 4; ++ni)
                    acc[mi][ni] = __builtin_amdgcn_mfma_f32_16x16x32_f16(af[mi], bfv[ni], acc[mi][ni], 0, 0, 0);
        }
        __syncthreads();
    }

    float bv[4];
#pragma unroll
    for (int ni = 0; ni < 4; ++ni) bv[ni] = bias[bn0 + wc + ni * 16 + l16];
#pragma unroll
    for (int mi = 0; mi < 4; ++mi) {
#pragma unroll
        for (int r = 0; r < 4; ++r) {
            size_t row = (size_t)(bm0 + wr + mi * 16 + quad * 4 + r);
            f16* crow = C + row * HID + bn0 + wc + l16;
#pragma unroll
            for (int ni = 0; ni < 4; ++ni) {
                float v = acc[mi][ni][r] + bv[ni];
                if (RELU) v = fmaxf(v, 0.f);
                crow[ni * 16] = (f16)v;
            }
        }
    }
}

// ---------------- output head: out[N][2] = h @ W[256][2] + b ----------------
__global__ void k_out(const uint2* __restrict__ h, const float* __restrict__ W,
                      const float* __restrict__ b, float* __restrict__ out, int n) {
    int gw = (blockIdx.x * 256 + threadIdx.x) >> 6;
    if (gw >= n) return;
    int lane = threadIdx.x & 63;
    uint2 d = h[(size_t)gw * 64 + lane];
    float x0, x1, x2, x3;
    unpack2(d.x, x0, x1); unpack2(d.y, x2, x3);
    int k = lane * 4;
    float o0 = x0 * W[k * 2 + 0] + x1 * W[k * 2 + 2] + x2 * W[k * 2 + 4] + x3 * W[k * 2 + 6];
    float o1 = x0 * W[k * 2 + 1] + x1 * W[k * 2 + 3] + x2 * W[k * 2 + 5] + x3 * W[k * 2 + 7];
#pragma unroll
    for (int off = 32; off > 0; off >>= 1) {
        o0 += __shfl_down(o0, off);
        o1 += __shfl_down(o1, off);
    }
    if (lane == 0) {
        out[(size_t)gw * 2 + 0] = o0 + b[0];
        out[(size_t)gw * 2 + 1] = o1 + b[1];
    }
}

extern "C" void kernel_launch(void* const* d_in, const int* in_sizes, int n_in,
                              void* d_out, int out_size, void* d_ws, size_t ws_size,
                              hipStream_t stream) {
    const float* x    = (const float*)d_in[0];
    const int*   ei   = (const int*)d_in[1];
    const int*   esrc = ei;
    const int*   edst = ei + N_EDGES;
    const float* lw[3][8];
    for (int l = 0; l < 3; ++l)
        for (int j = 0; j < 8; ++j) lw[l][j] = (const float*)d_in[2 + l * 8 + j];
    const float* outW = (const float*)d_in[26];
    const float* outB = (const float*)d_in[27];

    char* base = (char*)d_ws;
    size_t off = 0;
    auto alloc = [&](size_t bytes) -> void* {
        void* r = base + off;
        off += (bytes + 255) & ~(size_t)255;
        return r;
    };
    f16* z  = (f16*)alloc((size_t)MPAD * 256 * 2);
    f16* y  = (f16*)alloc((size_t)MPAD * 256 * 2);
    f16* h  = (f16*)alloc((size_t)MPAD * 256 * 2);
    f16* xh = (f16*)alloc((size_t)MPAD * 128 * 2);
    f16* W1t[3]; float* bias1[3]; f16* W2t[3];
    W1t[0] = (f16*)alloc(256 * 128 * 2);
    W1t[1] = (f16*)alloc(256 * 256 * 2);
    W1t[2] = (f16*)alloc(256 * 256 * 2);
    for (int l = 0; l < 3; ++l) W2t[l] = (f16*)alloc(256 * 256 * 2);
    for (int l = 0; l < 3; ++l) bias1[l] = (float*)alloc(256 * 4);
    unsigned* pairs = (unsigned*)alloc((size_t)NBUCK * BSTRIDE * 4);
    int* nb     = (int*)alloc(NBUCK * 4);
    int* bbase  = (int*)alloc(NBUCK * 4);
    int* rowptr = (int*)alloc((size_t)(N_NODES + 1) * 4);
    int* colidx = (int*)alloc((size_t)N_EDGES * 4);

    // CSR build (bucketed counting sort)
    hipMemsetAsync(nb, 0, NBUCK * 4, stream);
    k_bucketA<<<(N_EDGES + 4095) / 4096, 256, 0, stream>>>(esrc, edst, pairs, nb, N_EDGES);
    k_scan196<<<1, 256, 0, stream>>>(nb, bbase, rowptr + N_NODES);
    k_bucketB<<<NBUCK, 256, 0, stream>>>(pairs, nb, bbase, rowptr, colidx);

    // dtype prep
    k_cvt<<<(N_NODES * 64 + 255) / 256, 256, 0, stream>>>((const float2*)x, (unsigned*)xh, N_NODES * 64);
    k_foldw1<<<128, 256, 0, stream>>>(lw[0][0], lw[0][1], lw[0][2], lw[0][3], lw[0][4], lw[0][5], W1t[0], bias1[0], 128);
    k_foldw1<<<256, 256, 0, stream>>>(lw[1][0], lw[1][1], lw[1][2], lw[1][3], lw[1][4], lw[1][5], W1t[1], bias1[1], 256);
    k_foldw1<<<256, 256, 0, stream>>>(lw[2][0], lw[2][1], lw[2][2], lw[2][3], lw[2][4], lw[2][5], W1t[2], bias1[2], 256);
    for (int l = 0; l < 3; ++l)
        k_transb<<<256, 256, 0, stream>>>(lw[l][6], W2t[l]);

    const dim3 ggrid(MPAD / 128, 2);
    const int AGG_BLOCKS = (N_NODES + 3) / 4;

    // layer 1
    k_agg128<<<AGG_BLOCKS, 256, 0, stream>>>((const unsigned*)xh, rowptr, colidx, (unsigned*)z, N_NODES);
    k_gemm<128, true><<<ggrid, 256, 0, stream>>>(z, W1t[0], bias1[0], y);
    k_gemm<256, true><<<ggrid, 256, 0, stream>>>(y, W2t[0], lw[0][7], h);
    // layer 2
    k_agg256<<<AGG_BLOCKS, 256, 0, stream>>>((const uint2*)h, rowptr, colidx, (uint2*)z, N_NODES);
    k_gemm<256, true><<<ggrid, 256, 0, stream>>>(z, W1t[1], bias1[1], y);
    k_gemm<256, true><<<ggrid, 256, 0, stream>>>(y, W2t[1], lw[1][7], h);
    // layer 3
    k_agg256<<<AGG_BLOCKS, 256, 0, stream>>>((const uint2*)h, rowptr, colidx, (uint2*)z, N_NODES);
    k_gemm<256, true><<<ggrid, 256, 0, stream>>>(z, W1t[2], bias1[2], y);
    k_gemm<256, false><<<ggrid, 256, 0, stream>>>(y, W2t[2], lw[2][7], h);
    // output head
    k_out<<<AGG_BLOCKS, 256, 0, stream>>>((const uint2*)h, outW, outB, (float*)d_out, N_NODES);
}

// Round 3
// 1008.507 us; speedup vs baseline: 1.2623x; 1.0608x over previous
//
#include <hip/hip_runtime.h>
#include <cstdint>
#include <cstddef>

#define N_NODES 100000
#define N_EDGES 3200000
#define MPAD    100096   // 782 * 128
#define HID     256
#define NBUCK   196      // ceil(100000/512) buckets of 512 nodes
#define BSH     9        // 512 nodes per bucket
#define BSTRIDE 18432    // bucket region capacity (mean 16384 + 16 sigma)

typedef _Float16 f16;
typedef _Float16 f16x8 __attribute__((ext_vector_type(8)));
typedef float    f32x4 __attribute__((ext_vector_type(4)));

union F16x2 { unsigned u; f16 h[2]; };
__device__ inline void unpack2(unsigned u, float& a, float& b) {
    F16x2 x; x.u = u; a = (float)x.h[0]; b = (float)x.h[1];
}
__device__ inline unsigned pack2(float a, float b) {
    F16x2 x; x.h[0] = (f16)a; x.h[1] = (f16)b; return x.u;
}

// ---------------- CSR build: bucketed counting sort ----------------
__global__ __launch_bounds__(256) void k_bucketA(const int* __restrict__ src,
                                                 const int* __restrict__ dst,
                                                 unsigned* __restrict__ pairs,
                                                 int* __restrict__ nb, int e) {
    __shared__ int hist[NBUCK];
    __shared__ int lbase[NBUCK];
    __shared__ int lcur[NBUCK];
    const int t = threadIdx.x;
    for (int i = t; i < NBUCK; i += 256) hist[i] = 0;
    __syncthreads();
    const int e0 = blockIdx.x * 4096;
    bool v[16]; int d[16], s[16];
#pragma unroll
    for (int i = 0; i < 16; ++i) {
        int idx = e0 + i * 256 + t;
        v[i] = idx < e;
        d[i] = v[i] ? dst[idx] : 0;
        s[i] = v[i] ? src[idx] : 0;
    }
#pragma unroll
    for (int i = 0; i < 16; ++i)
        if (v[i]) atomicAdd(&hist[d[i] >> BSH], 1);
    __syncthreads();
    for (int i = t; i < NBUCK; i += 256) {
        int h = hist[i];
        lbase[i] = h ? atomicAdd(&nb[i], h) : 0;
        lcur[i] = 0;
    }
    __syncthreads();
#pragma unroll
    for (int i = 0; i < 16; ++i) {
        if (v[i]) {
            int b = d[i] >> BSH;
            int p = atomicAdd(&lcur[b], 1);
            unsigned packed = ((unsigned)(d[i] & 511) << 17) | (unsigned)s[i];
            pairs[(size_t)b * BSTRIDE + lbase[b] + p] = packed;
        }
    }
}

__global__ void k_scan196(const int* __restrict__ nb, int* __restrict__ bbase,
                          int* __restrict__ rowptrN) {
    __shared__ int s[256];
    int t = threadIdx.x;
    int v = (t < NBUCK) ? nb[t] : 0;
    s[t] = v;
    __syncthreads();
    for (int off = 1; off < 256; off <<= 1) {
        int u = (t >= off) ? s[t - off] : 0;
        __syncthreads();
        s[t] += u;
        __syncthreads();
    }
    if (t < NBUCK) bbase[t] = s[t] - v;
    if (t == 0) *rowptrN = N_EDGES;
}

__global__ __launch_bounds__(256) void k_bucketB(const unsigned* __restrict__ pairs,
                                                 const int* __restrict__ nb,
                                                 const int* __restrict__ bbase,
                                                 int* __restrict__ rowptr,
                                                 int* __restrict__ colidx) {
    __shared__ int deg[512];
    __shared__ int sc[512];
    __shared__ int cur[512];
    const int b = blockIdx.x, t = threadIdx.x;
    const int cnt = nb[b], base = bbase[b];
    const unsigned* P = pairs + (size_t)b * BSTRIDE;
    deg[t] = 0; deg[t + 256] = 0;
    __syncthreads();
    for (int i = t; i < cnt; i += 256) atomicAdd(&deg[P[i] >> 17], 1);
    __syncthreads();
    sc[t] = deg[t]; sc[t + 256] = deg[t + 256];
    __syncthreads();
    for (int off = 1; off < 512; off <<= 1) {
        int a0 = (t >= off) ? sc[t - off] : 0;
        int a1 = (t + 256 >= off) ? sc[t + 256 - off] : 0;
        __syncthreads();
        sc[t] += a0; sc[t + 256] += a1;
        __syncthreads();
    }
    int node0 = b << BSH;
#pragma unroll
    for (int rep = 0; rep < 2; ++rep) {
        int i = t + rep * 256;
        int excl = base + sc[i] - deg[i];
        cur[i] = excl;
        int node = node0 + i;
        if (node < N_NODES) rowptr[node] = excl;
    }
    __syncthreads();
    for (int i = t; i < cnt; i += 256) {
        unsigned p = P[i];
        int pos = atomicAdd(&cur[p >> 17], 1);
        colidx[pos] = (int)(p & 0x1FFFF);
    }
}

// Sort each node's neighbor list ascending by src (64-lane bitonic).
// Pure perf transform: sorted adjacency makes concurrent waves sweep h
// monotonically -> narrow sliding src window -> L2 hits. deg>64 rows skipped.
__global__ void k_sortrows(const int* __restrict__ rp, int* __restrict__ ci, int n) {
    int gw = (blockIdx.x * 256 + threadIdx.x) >> 6;
    if (gw >= n) return;
    int lane = threadIdx.x & 63;
    int s = rp[gw], e = rp[gw + 1];
    int deg = e - s;
    if (deg <= 1 || deg > 64) return;   // wave-uniform branch
    int v = (lane < deg) ? ci[s + lane] : 0x7FFFFFFF;
#pragma unroll
    for (int k = 2; k <= 64; k <<= 1) {
#pragma unroll
        for (int j = k >> 1; j > 0; j >>= 1) {
            int o = __shfl_xor(v, j);
            bool up = ((lane & k) == 0);
            bool lower = ((lane & j) == 0);
            int mn = min(v, o), mx = max(v, o);
            v = (lower == up) ? mn : mx;
        }
    }
    if (lane < deg) ci[s + lane] = v;
}

// ---------------- dtype prep ----------------
__global__ void k_cvt(const float2* __restrict__ x, unsigned* __restrict__ o, int n) {
    int t = blockIdx.x * 256 + threadIdx.x;
    if (t < n) { float2 v = x[t]; o[t] = pack2(v.x, v.y); }
}

__global__ void k_foldw1(const float* __restrict__ W, const float* __restrict__ b1,
                         const float* __restrict__ gm, const float* __restrict__ bt,
                         const float* __restrict__ mu, const float* __restrict__ vr,
                         f16* __restrict__ Wt, float* __restrict__ bias, int K) {
    int t = blockIdx.x * 256 + threadIdx.x;
    if (t >= K * 256) return;
    int n = t & 255, k = t >> 8;
    float sc = gm[n] * rsqrtf(vr[n] + 1e-5f);
    Wt[n * K + k] = (f16)(W[t] * sc);
    if (k == 0) bias[n] = (b1[n] - mu[n]) * sc + bt[n];
}

__global__ void k_transb(const float* __restrict__ W, f16* __restrict__ Wt) {
    int t = blockIdx.x * 256 + threadIdx.x; // 65536
    int n = t & 255, k = t >> 8;
    Wt[n * 256 + k] = (f16)W[t];
}

// ---------------- aggregation: z = h + sum_{j->i} h_j ----------------
__global__ void k_agg256(const uint2* __restrict__ h, const int* __restrict__ rp,
                         const int* __restrict__ ci, uint2* __restrict__ z, int n) {
    int gw = (blockIdx.x * 256 + threadIdx.x) >> 6;
    if (gw >= n) return;
    int lane = threadIdx.x & 63;
    uint2 d = h[(size_t)gw * 64 + lane];
    float a0, a1, a2, a3, t0, t1;
    unpack2(d.x, a0, a1); unpack2(d.y, a2, a3);
    int s = rp[gw], e = rp[gw + 1];
    int p = s;
    for (; p + 3 < e; p += 4) {
        int j0 = ci[p], j1 = ci[p + 1], j2 = ci[p + 2], j3 = ci[p + 3];
        uint2 d0 = h[(size_t)j0 * 64 + lane];
        uint2 d1 = h[(size_t)j1 * 64 + lane];
        uint2 d2 = h[(size_t)j2 * 64 + lane];
        uint2 d3 = h[(size_t)j3 * 64 + lane];
        unpack2(d0.x, t0, t1); a0 += t0; a1 += t1;
        unpack2(d0.y, t0, t1); a2 += t0; a3 += t1;
        unpack2(d1.x, t0, t1); a0 += t0; a1 += t1;
        unpack2(d1.y, t0, t1); a2 += t0; a3 += t1;
        unpack2(d2.x, t0, t1); a0 += t0; a1 += t1;
        unpack2(d2.y, t0, t1); a2 += t0; a3 += t1;
        unpack2(d3.x, t0, t1); a0 += t0; a1 += t1;
        unpack2(d3.y, t0, t1); a2 += t0; a3 += t1;
    }
    for (; p < e; ++p) {
        uint2 d0 = h[(size_t)ci[p] * 64 + lane];
        unpack2(d0.x, t0, t1); a0 += t0; a1 += t1;
        unpack2(d0.y, t0, t1); a2 += t0; a3 += t1;
    }
    uint2 o; o.x = pack2(a0, a1); o.y = pack2(a2, a3);
    z[(size_t)gw * 64 + lane] = o;
}

__global__ void k_agg128(const unsigned* __restrict__ h, const int* __restrict__ rp,
                         const int* __restrict__ ci, unsigned* __restrict__ z, int n) {
    int gw = (blockIdx.x * 256 + threadIdx.x) >> 6;
    if (gw >= n) return;
    int lane = threadIdx.x & 63;
    float a0, a1, t0, t1;
    unpack2(h[(size_t)gw * 64 + lane], a0, a1);
    int s = rp[gw], e = rp[gw + 1];
    int p = s;
    for (; p + 3 < e; p += 4) {
        int j0 = ci[p], j1 = ci[p + 1], j2 = ci[p + 2], j3 = ci[p + 3];
        unsigned d0 = h[(size_t)j0 * 64 + lane];
        unsigned d1 = h[(size_t)j1 * 64 + lane];
        unsigned d2 = h[(size_t)j2 * 64 + lane];
        unsigned d3 = h[(size_t)j3 * 64 + lane];
        unpack2(d0, t0, t1); a0 += t0; a1 += t1;
        unpack2(d1, t0, t1); a0 += t0; a1 += t1;
        unpack2(d2, t0, t1); a0 += t0; a1 += t1;
        unpack2(d3, t0, t1); a0 += t0; a1 += t1;
    }
    for (; p < e; ++p) {
        unpack2(h[(size_t)ci[p] * 64 + lane], t0, t1); a0 += t0; a1 += t1;
    }
    z[(size_t)gw * 64 + lane] = pack2(a0, a1);
}

// ---------------- GEMM: C[MPAD][256] = A[MPAD][K] @ Bt[256][K]^T (+bias, relu) ----------------
template <int K, bool RELU>
__global__ __launch_bounds__(256) void k_gemm(const f16* __restrict__ A,
                                              const f16* __restrict__ Bt,
                                              const float* __restrict__ bias,
                                              f16* __restrict__ C) {
    __shared__ f16 As[128 * 64];
    __shared__ f16 Bs[128 * 64];
    const int tid = threadIdx.x;
    const int bm0 = blockIdx.x * 128;
    const int bn0 = blockIdx.y * 128;
    const int lane = tid & 63, wave = tid >> 6;
    const int quad = lane >> 4, l16 = lane & 15;
    const int wr = (wave >> 1) * 64, wc = (wave & 1) * 64;
    f32x4 acc[4][4] = {};
    const f16* Abase = A + (size_t)bm0 * K;
    const f16* Bbase = Bt + (size_t)bn0 * K;

    for (int k0 = 0; k0 < K; k0 += 64) {
#pragma unroll
        for (int i = 0; i < 4; ++i) {
            int c = i * 256 + tid;
            int m = c >> 3;
            int gg = (c & 7) ^ (m & 7);
            __builtin_amdgcn_global_load_lds(
                (const __attribute__((address_space(1))) unsigned int*)(Abase + (size_t)m * K + k0 + gg * 8),
                (__attribute__((address_space(3))) unsigned int*)(As + (size_t)c * 8), 16, 0, 0);
            __builtin_amdgcn_global_load_lds(
                (const __attribute__((address_space(1))) unsigned int*)(Bbase + (size_t)m * K + k0 + gg * 8),
                (__attribute__((address_space(3))) unsigned int*)(Bs + (size_t)c * 8), 16, 0, 0);
        }
        __syncthreads();
#pragma unroll
        for (int kk = 0; kk < 64; kk += 32) {
            const int gbase = kk >> 3;
            f16x8 af[4], bfv[4];
#pragma unroll
            for (int mi = 0; mi < 4; ++mi) {
                int m = wr + mi * 16 + l16;
                int slot = (gbase + quad) ^ (m & 7);
                af[mi] = *(const f16x8*)&As[(m * 8 + slot) * 8];
            }
#pragma unroll
            for (int ni = 0; ni < 4; ++ni) {
                int m = wc + ni * 16 + l16;
                int slot = (gbase + quad) ^ (m & 7);
                bfv[ni] = *(const f16x8*)&Bs[(m * 8 + slot) * 8];
            }
#pragma unroll
            for (int mi = 0; mi < 4; ++mi)
#pragma unroll
                for (int ni = 0; ni < 4; ++ni)
                    acc[mi][ni] = __builtin_amdgcn_mfma_f32_16x16x32_f16(af[mi], bfv[ni], acc[mi][ni], 0, 0, 0);
        }
        __syncthreads();
    }

    float bv[4];
#pragma unroll
    for (int ni = 0; ni < 4; ++ni) bv[ni] = bias[bn0 + wc + ni * 16 + l16];
#pragma unroll
    for (int mi = 0; mi < 4; ++mi) {
#pragma unroll
        for (int r = 0; r < 4; ++r) {
            size_t row = (size_t)(bm0 + wr + mi * 16 + quad * 4 + r);
            f16* crow = C + row * HID + bn0 + wc + l16;
#pragma unroll
            for (int ni = 0; ni < 4; ++ni) {
                float v = acc[mi][ni][r] + bv[ni];
                if (RELU) v = fmaxf(v, 0.f);
                crow[ni * 16] = (f16)v;
            }
        }
    }
}

// ---------------- output head ----------------
__global__ void k_out(const uint2* __restrict__ h, const float* __restrict__ W,
                      const float* __restrict__ b, float* __restrict__ out, int n) {
    int gw = (blockIdx.x * 256 + threadIdx.x) >> 6;
    if (gw >= n) return;
    int lane = threadIdx.x & 63;
    uint2 d = h[(size_t)gw * 64 + lane];
    float x0, x1, x2, x3;
    unpack2(d.x, x0, x1); unpack2(d.y, x2, x3);
    int k = lane * 4;
    float o0 = x0 * W[k * 2 + 0] + x1 * W[k * 2 + 2] + x2 * W[k * 2 + 4] + x3 * W[k * 2 + 6];
    float o1 = x0 * W[k * 2 + 1] + x1 * W[k * 2 + 3] + x2 * W[k * 2 + 5] + x3 * W[k * 2 + 7];
#pragma unroll
    for (int off = 32; off > 0; off >>= 1) {
        o0 += __shfl_down(o0, off);
        o1 += __shfl_down(o1, off);
    }
    if (lane == 0) {
        out[(size_t)gw * 2 + 0] = o0 + b[0];
        out[(size_t)gw * 2 + 1] = o1 + b[1];
    }
}

extern "C" void kernel_launch(void* const* d_in, const int* in_sizes, int n_in,
                              void* d_out, int out_size, void* d_ws, size_t ws_size,
                              hipStream_t stream) {
    const float* x    = (const float*)d_in[0];
    const int*   ei   = (const int*)d_in[1];
    const int*   esrc = ei;
    const int*   edst = ei + N_EDGES;
    const float* lw[3][8];
    for (int l = 0; l < 3; ++l)
        for (int j = 0; j < 8; ++j) lw[l][j] = (const float*)d_in[2 + l * 8 + j];
    const float* outW = (const float*)d_in[26];
    const float* outB = (const float*)d_in[27];

    char* base = (char*)d_ws;
    size_t off = 0;
    auto alloc = [&](size_t bytes) -> void* {
        void* r = base + off;
        off += (bytes + 255) & ~(size_t)255;
        return r;
    };
    f16* z  = (f16*)alloc((size_t)MPAD * 256 * 2);
    f16* y  = (f16*)alloc((size_t)MPAD * 256 * 2);
    f16* h  = (f16*)alloc((size_t)MPAD * 256 * 2);
    f16* xh = (f16*)alloc((size_t)MPAD * 128 * 2);
    f16* W1t[3]; float* bias1[3]; f16* W2t[3];
    W1t[0] = (f16*)alloc(256 * 128 * 2);
    W1t[1] = (f16*)alloc(256 * 256 * 2);
    W1t[2] = (f16*)alloc(256 * 256 * 2);
    for (int l = 0; l < 3; ++l) W2t[l] = (f16*)alloc(256 * 256 * 2);
    for (int l = 0; l < 3; ++l) bias1[l] = (float*)alloc(256 * 4);
    unsigned* pairs = (unsigned*)alloc((size_t)NBUCK * BSTRIDE * 4);
    int* nb     = (int*)alloc(NBUCK * 4);
    int* bbase  = (int*)alloc(NBUCK * 4);
    int* rowptr = (int*)alloc((size_t)(N_NODES + 1) * 4);
    int* colidx = (int*)alloc((size_t)N_EDGES * 4);

    // CSR build (bucketed counting sort) + per-row src sort
    hipMemsetAsync(nb, 0, NBUCK * 4, stream);
    k_bucketA<<<(N_EDGES + 4095) / 4096, 256, 0, stream>>>(esrc, edst, pairs, nb, N_EDGES);
    k_scan196<<<1, 256, 0, stream>>>(nb, bbase, rowptr + N_NODES);
    k_bucketB<<<NBUCK, 256, 0, stream>>>(pairs, nb, bbase, rowptr, colidx);
    const int AGG_BLOCKS = (N_NODES + 3) / 4;
    k_sortrows<<<AGG_BLOCKS, 256, 0, stream>>>(rowptr, colidx, N_NODES);

    // dtype prep
    k_cvt<<<(N_NODES * 64 + 255) / 256, 256, 0, stream>>>((const float2*)x, (unsigned*)xh, N_NODES * 64);
    k_foldw1<<<128, 256, 0, stream>>>(lw[0][0], lw[0][1], lw[0][2], lw[0][3], lw[0][4], lw[0][5], W1t[0], bias1[0], 128);
    k_foldw1<<<256, 256, 0, stream>>>(lw[1][0], lw[1][1], lw[1][2], lw[1][3], lw[1][4], lw[1][5], W1t[1], bias1[1], 256);
    k_foldw1<<<256, 256, 0, stream>>>(lw[2][0], lw[2][1], lw[2][2], lw[2][3], lw[2][4], lw[2][5], W1t[2], bias1[2], 256);
    for (int l = 0; l < 3; ++l)
        k_transb<<<256, 256, 0, stream>>>(lw[l][6], W2t[l]);

    const dim3 ggrid(MPAD / 128, 2);

    // layer 1
    k_agg128<<<AGG_BLOCKS, 256, 0, stream>>>((const unsigned*)xh, rowptr, colidx, (unsigned*)z, N_NODES);
    k_gemm<128, true><<<ggrid, 256, 0, stream>>>(z, W1t[0], bias1[0], y);
    k_gemm<256, true><<<ggrid, 256, 0, stream>>>(y, W2t[0], lw[0][7], h);
    // layer 2
    k_agg256<<<AGG_BLOCKS, 256, 0, stream>>>((const uint2*)h, rowptr, colidx, (uint2*)z, N_NODES);
    k_gemm<256, true><<<ggrid, 256, 0, stream>>>(z, W1t[1], bias1[1], y);
    k_gemm<256, true><<<ggrid, 256, 0, stream>>>(y, W2t[1], lw[1][7], h);
    // layer 3
    k_agg256<<<AGG_BLOCKS, 256, 0, stream>>>((const uint2*)h, rowptr, colidx, (uint2*)z, N_NODES);
    k_gemm<256, true><<<ggrid, 256, 0, stream>>>(z, W1t[2], bias1[2], y);
    k_gemm<256, false><<<ggrid, 256, 0, stream>>>(y, W2t[2], lw[2][7], h);
    // output head
    k_out<<<AGG_BLOCKS, 256, 0, stream>>>((const uint2*)h, outW, outB, (float*)d_out, N_NODES);
}